// Round 1
// baseline (166.106 us; speedup 1.0000x reference)
//
#include <hip/hip_runtime.h>
#include <hip/hip_bf16.h>

// LineCNNSimple: 1024 x (conv3x3 1->64, relu, conv3x3 64->64, relu, maxpool2,
// fc 12544->128 relu, fc 128->83) on 28x28 windows. bf16 MFMA pipeline.
//
// ws layout (bytes), total 30,609,408:
//   XW   @0        : 1024*784 bf16 windowed input
//   WB1  @1605632  : conv1 W frag-order [4nt][64lane][8]
//   WB2  @1609728  : conv2 W frag-order [4nt][18ks][64lane][8], k=(dy*3+dx)*64+ci
//   WFC1 @1683456  : fc1 W frag-order [8nt][392ks][64lane][8], k'=(oyp*14+oxp)*64+co
//   WFC2 @4894720  : fc2 W frag-order [6nt][4ks][64lane][8] (cls>=83 zeroed)
//   POOL @4919296  : pooled activations [1024][12544] bf16 (k'-order)

typedef __attribute__((ext_vector_type(8))) short short8;
typedef __attribute__((ext_vector_type(4))) float f32x4;

#define XW_OFF   0u
#define WB1_OFF  1605632u
#define WB2_OFF  1609728u
#define WFC1_OFF 1683456u
#define WFC2_OFF 4894720u
#define POOL_OFF 4919296u

__device__ __forceinline__ unsigned short f2bf(float f) {
  unsigned u = __float_as_uint(f);
  u += 0x7fffu + ((u >> 16) & 1u);   // round-to-nearest-even
  return (unsigned short)(u >> 16);
}
// elementwise u16 max of two packed non-negative bf16 (bit order == value order)
__device__ __forceinline__ unsigned pkmax16(unsigned a, unsigned b) {
  unsigned lo = ((a & 0xffffu) > (b & 0xffffu)) ? (a & 0xffffu) : (b & 0xffffu);
  unsigned hi = ((a >> 16) > (b >> 16)) ? (a & 0xffff0000u) : (b & 0xffff0000u);
  return lo | hi;
}

// ---------------- prep: repack weights/input to bf16 frag order ----------------
__global__ __launch_bounds__(256) void prep_kernel(
    const float* __restrict__ x, const float* __restrict__ w1,
    const float* __restrict__ w2, const float* __restrict__ wfc1,
    const float* __restrict__ wfc2, unsigned short* __restrict__ ws16)
{
  int i = blockIdx.x * blockDim.x + threadIdx.x;
  const int T0 = 802816;            // xw
  const int T1 = T0 + 2048;         // wb1
  const int T2 = T1 + 36864;        // wb2
  const int T3 = T2 + 1605632;      // wfc1
  const int T4 = T3 + 12288;        // wfc2
  if (i < T0) {
    int n = i / 784, r = i % 784;
    int y = r / 28, xx = r % 28;
    int b = n >> 5, s = n & 31;
    ws16[XW_OFF / 2 + i] = f2bf(x[b * 25088 + y * 896 + s * 28 + xx]);
  } else if (i < T1) {
    int i2 = i - T0;
    int j = i2 & 7, l = (i2 >> 3) & 63, nt = i2 >> 9;
    int n = nt * 16 + (l & 15), k = 8 * (l >> 4) + j;
    float v = (k < 9) ? w1[n * 9 + k] : 0.f;
    ws16[WB1_OFF / 2 + i2] = f2bf(v);
  } else if (i < T2) {
    int i2 = i - T1;
    int j = i2 & 7, l = (i2 >> 3) & 63, rest = i2 >> 9;
    int ks = rest % 18, nt = rest / 18;
    int n = nt * 16 + (l & 15);
    int kk = ks * 32 + 8 * (l >> 4) + j;
    int dydx = kk >> 6, ci = kk & 63;
    ws16[WB2_OFF / 2 + i2] = f2bf(w2[n * 576 + ci * 9 + dydx]);
  } else if (i < T3) {
    int i2 = i - T2;
    int j = i2 & 7, l = (i2 >> 3) & 63, rest = i2 >> 9;
    int ks = rest % 392, nt = rest / 392;
    int fcn = nt * 16 + (l & 15);
    int kp = ks * 32 + 8 * (l >> 4) + j;
    int co = kp & 63, r2 = kp >> 6;
    int oxp = r2 % 14, oyp = r2 / 14;
    ws16[WFC1_OFF / 2 + i2] = f2bf(wfc1[fcn * 12544 + co * 196 + oyp * 14 + oxp]);
  } else if (i < T4) {
    int i2 = i - T3;
    int j = i2 & 7, l = (i2 >> 3) & 63, rest = i2 >> 9;
    int ks = rest & 3, nt = rest >> 2;
    int cls = nt * 16 + (l & 15);
    int k = ks * 32 + 8 * (l >> 4) + j;
    float v = (cls < 83) ? wfc2[cls * 128 + k] : 0.f;
    ws16[WFC2_OFF / 2 + i2] = f2bf(v);
  }
}

// ---------------- fused conv1+conv2+pool, one image per block ----------------
// LDS: lds1 = padded conv1 output [30][30][64] bf16 (swizzled), 115200 B
//      xpool = x-then-y pooled staging [16][14][64] bf16, 28672 B
//      xw    = raw 28x28 bf16 window, 1568 B                    total 145440 B
__global__ __launch_bounds__(512, 2) void conv_kernel(
    const float* __restrict__ c1b, const float* __restrict__ c2b,
    unsigned short* __restrict__ ws16)
{
  extern __shared__ char smem[];
  unsigned short* lds1  = (unsigned short*)smem;
  unsigned short* xpool = (unsigned short*)(smem + 115200);
  unsigned short* xw    = (unsigned short*)(smem + 143872);

  const int tid = threadIdx.x;
  const int wave = tid >> 6, lane = tid & 63;
  const int g = lane >> 4, l15 = lane & 15;
  const int n = blockIdx.x;

  const unsigned short* xw_g = ws16 + XW_OFF / 2 + n * 784;
  const short8* wb1 = (const short8*)(ws16 + WB1_OFF / 2);
  const short8* wb2 = (const short8*)(ws16 + WB2_OFF / 2);
  unsigned* pool_g = (unsigned*)(ws16 + POOL_OFF / 2) + n * 6272;

  short8 z8 = {0, 0, 0, 0, 0, 0, 0, 0};
  // zero lds1 (pads included), stage raw window
  short8* lds1v = (short8*)lds1;
  for (int idx = tid; idx < 7200; idx += 512) lds1v[idx] = z8;
  if (tid < 98) ((short8*)xw)[tid] = ((const short8*)xw_g)[tid];
  __syncthreads();

  // ---- conv1 via MFMA: M=784 spatial, N=64 co, K=9 (padded to 32), 1 k-step
  short8 b1f[4];
#pragma unroll
  for (int nt = 0; nt < 4; ++nt) b1f[nt] = wb1[nt * 64 + lane];
  float c1bv[4];
#pragma unroll
  for (int nt = 0; nt < 4; ++nt) c1bv[nt] = c1b[nt * 16 + l15];

  for (int mt = wave; mt < 49; mt += 8) {
    int m = mt * 16 + l15;
    int oy = m / 28, ox = m % 28;
    short8 a = z8;
#pragma unroll
    for (int j = 0; j < 8; ++j) {
      int k = 8 * g + j;
      int dy = (k >= 6) ? 2 : ((k >= 3) ? 1 : 0);
      int dx = k - 3 * dy;
      int iy = oy + dy - 1, ix = ox + dx - 1;
      bool valid = (k < 9) && (iy >= 0) && (iy < 28) && (ix >= 0) && (ix < 28);
      int idx = valid ? (iy * 28 + ix) : 0;
      unsigned short v = xw[idx];
      a[j] = valid ? (short)v : (short)0;
    }
    f32x4 d[4];
#pragma unroll
    for (int nt = 0; nt < 4; ++nt) {
      f32x4 zz = {0.f, 0.f, 0.f, 0.f};
      d[nt] = __builtin_amdgcn_mfma_f32_16x16x32_bf16(a, b1f[nt], zz, 0, 0, 0);
    }
    // D: row = 4*g+i, col = nt*16+l15  -> bias+relu -> swizzled LDS store
#pragma unroll
    for (int i = 0; i < 4; ++i) {
      int mm = mt * 16 + 4 * g + i;
      int oy2 = mm / 28, ox2 = mm % 28;
      int sp = (oy2 + 1) * 30 + (ox2 + 1);
      unsigned base = (unsigned)sp * 128u;
      unsigned swz = ((unsigned)sp & 7u) << 4;
#pragma unroll
      for (int nt = 0; nt < 4; ++nt) {
        int co = nt * 16 + l15;
        float v = fmaxf(d[nt][i] + c1bv[nt], 0.f);
        *(unsigned short*)(smem + (base + (((unsigned)(co * 2)) ^ swz))) = f2bf(v);
      }
    }
  }
  __syncthreads();

  // ---- conv2 implicit GEMM: M=784, N=64, K=576 (18 k-steps of 32)
  const int ntp = (wave < 4) ? 0 : 2;   // wave's N-tile pair
  const int mg = wave & 3;              // wave's M-group
  float c2bv[2];
#pragma unroll
  for (int tn = 0; tn < 2; ++tn) c2bv[tn] = c2b[(ntp + tn) * 16 + l15];

#pragma unroll 1
  for (int hf = 0; hf < 2; ++hf) {      // output rows [0,16) then [16,28)
    const int r0 = hf * 16;
    const int Mh = hf ? 21 : 28;        // M-tiles this half
    const int prows = hf ? 6 : 8;       // pooled rows this half
    f32x4 acc[7][2];
#pragma unroll
    for (int mi = 0; mi < 7; ++mi) {
      f32x4 zz = {0.f, 0.f, 0.f, 0.f};
      acc[mi][0] = zz; acc[mi][1] = zz;
    }
#pragma unroll 1
    for (int phase = 0; phase < 2; ++phase) {   // k-steps [0,9) then [9,18)
      short8 bfr[2][9];
#pragma unroll
      for (int tn = 0; tn < 2; ++tn)
#pragma unroll
        for (int ks = 0; ks < 9; ++ks)
          bfr[tn][ks] = wb2[((ntp + tn) * 18 + phase * 9 + ks) * 64 + lane];

#pragma unroll
      for (int mi = 0; mi < 7; ++mi) {
        int mt = mg + 4 * mi;
        if (mt < Mh) {                   // wave-uniform guard
          int m = mt * 16 + l15;
          int yloc = m / 28, ox = m % 28;
          int spb = (r0 + yloc) * 30 + ox;
#pragma unroll
          for (int ks = 0; ks < 9; ++ks) {
            int ksg = phase * 9 + ks;
            int dydx = ksg >> 1;
            int dy = (dydx >= 6) ? 2 : ((dydx >= 3) ? 1 : 0);
            int dx = dydx - 3 * dy;
            int ci0 = ((ksg & 1) << 5) + 8 * g;
            int sp = spb + dy * 30 + dx;           // ly=oy+dy, lx=ox+dx (pads absorb halo)
            unsigned off = (unsigned)sp * 128u +
                           (((unsigned)(ci0 * 2)) ^ ((((unsigned)sp) & 7u) << 4));
            short8 a = *(const short8*)(smem + off);
            acc[mi][0] = __builtin_amdgcn_mfma_f32_16x16x32_bf16(a, bfr[0][ks], acc[mi][0], 0, 0, 0);
            acc[mi][1] = __builtin_amdgcn_mfma_f32_16x16x32_bf16(a, bfr[1][ks], acc[mi][1], 0, 0, 0);
          }
        }
      }
    }
    // epilogue: bias+relu, x-pool (adjacent acc regs), stash in xpool LDS
#pragma unroll
    for (int mi = 0; mi < 7; ++mi) {
      int mt = mg + 4 * mi;
      if (mt < Mh) {
#pragma unroll
        for (int tn = 0; tn < 2; ++tn) {
          int co = (ntp + tn) * 16 + l15;
#pragma unroll
          for (int ip = 0; ip < 2; ++ip) {
            int mm = mt * 16 + 4 * g + 2 * ip;
            float v0 = fmaxf(acc[mi][tn][2 * ip] + c2bv[tn], 0.f);
            float v1 = fmaxf(acc[mi][tn][2 * ip + 1] + c2bv[tn], 0.f);
            float p = fmaxf(v0, v1);
            int yloc = mm / 28, oxp = (mm % 28) >> 1;
            xpool[(yloc * 14 + oxp) * 64 + co] = f2bf(p);
          }
        }
      }
    }
    __syncthreads();
    // y-pool + write pooled (k' = (oyp*14+oxp)*64+co), u32-packed
    {
      unsigned* xp32 = (unsigned*)xpool;
      int total = prows * 14 * 32;
      for (int u = tid; u < total; u += 512) {
        int co2 = u & 31;
        int r2 = u >> 5;
        int oxp = r2 % 14, yp = r2 / 14;
        unsigned a0 = xp32[((2 * yp) * 14 + oxp) * 32 + co2];
        unsigned a1 = xp32[((2 * yp + 1) * 14 + oxp) * 32 + co2];
        pool_g[((hf * 8 + yp) * 14 + oxp) * 32 + co2] = pkmax16(a0, a1);
      }
    }
    __syncthreads();
  }
}

// ---------------- fc1 (M=16 img, N=128, K=12544) + fc2 (N=83 pad 96, K=128) ----
__global__ __launch_bounds__(512, 2) void fc_kernel(
    const float* __restrict__ b1, const float* __restrict__ b2,
    const unsigned short* __restrict__ ws16, float* __restrict__ out)
{
  __shared__ unsigned short A_s[16 * 264];   // pad 264 breaks 16-way bank conflict
  __shared__ unsigned short h_s[16 * 136];
  const int tid = threadIdx.x;
  const int wave = tid >> 6, lane = tid & 63;
  const int g = lane >> 4, l15 = lane & 15;
  const int n0 = blockIdx.x * 16;

  const short8* pool8 = (const short8*)(ws16 + POOL_OFF / 2);
  const short8* wf1 = (const short8*)(ws16 + WFC1_OFF / 2);
  const short8* wf2 = (const short8*)(ws16 + WFC2_OFF / 2);

  f32x4 accA = {0.f, 0.f, 0.f, 0.f}, accB = {0.f, 0.f, 0.f, 0.f};
  const int img_s = tid >> 5, ln_s = tid & 31;
#pragma unroll 1
  for (int c = 0; c < 49; ++c) {             // 49 chunks x 8 k-steps = 392
    ((short8*)A_s)[img_s * 33 + ln_s] = pool8[(n0 + img_s) * 1568 + c * 32 + ln_s];
    __syncthreads();
#pragma unroll
    for (int ks = 0; ks < 8; ++ks) {
      short8 b = wf1[(wave * 392 + c * 8 + ks) * 64 + lane];
      short8 a = ((const short8*)A_s)[l15 * 33 + ks * 4 + g];
      if (ks & 1) accB = __builtin_amdgcn_mfma_f32_16x16x32_bf16(a, b, accB, 0, 0, 0);
      else        accA = __builtin_amdgcn_mfma_f32_16x16x32_bf16(a, b, accA, 0, 0, 0);
    }
    __syncthreads();
  }
  int fcn = wave * 16 + l15;
  float bias1 = b1[fcn];
#pragma unroll
  for (int i = 0; i < 4; ++i) {
    float h = fmaxf(accA[i] + accB[i] + bias1, 0.f);
    h_s[(4 * g + i) * 136 + fcn] = f2bf(h);
  }
  __syncthreads();
  if (wave < 6) {
    f32x4 a2 = {0.f, 0.f, 0.f, 0.f};
#pragma unroll
    for (int ks = 0; ks < 4; ++ks) {
      short8 b = wf2[(wave * 4 + ks) * 64 + lane];
      short8 a = ((const short8*)h_s)[l15 * 17 + ks * 4 + g];
      a2 = __builtin_amdgcn_mfma_f32_16x16x32_bf16(a, b, a2, 0, 0, 0);
    }
    int cls = wave * 16 + l15;
    if (cls < 83) {
      float bias2 = b2[cls];
#pragma unroll
      for (int i = 0; i < 4; ++i) {
        int nimg = n0 + 4 * g + i;
        out[((nimg >> 5) * 83 + cls) * 32 + (nimg & 31)] = a2[i] + bias2;
      }
    }
  }
}

extern "C" void kernel_launch(void* const* d_in, const int* in_sizes, int n_in,
                              void* d_out, int out_size, void* d_ws, size_t ws_size,
                              hipStream_t stream)
{
  const float* x    = (const float*)d_in[0];
  const float* w1   = (const float*)d_in[1];
  const float* c1b  = (const float*)d_in[2];
  const float* w2   = (const float*)d_in[3];
  const float* c2b  = (const float*)d_in[4];
  const float* wfc1 = (const float*)d_in[5];
  const float* bfc1 = (const float*)d_in[6];
  const float* wfc2 = (const float*)d_in[7];
  const float* bfc2 = (const float*)d_in[8];
  unsigned short* ws16 = (unsigned short*)d_ws;
  float* out = (float*)d_out;
  // needs 30,609,408 B of workspace
  prep_kernel<<<9608, 256, 0, stream>>>(x, w1, w2, wfc1, wfc2, ws16);
  conv_kernel<<<1024, 512, 145440, stream>>>(c1b, c2b, ws16);
  fc_kernel<<<64, 512, 0, stream>>>(bfc1, bfc2, ws16, out);
}

// Round 2
// 110.180 us; speedup vs baseline: 1.5076x; 1.5076x over previous
//
#include <hip/hip_runtime.h>
#include <hip/hip_bf16.h>

// LineCNNSimple: 1024 x (conv3x3 1->64 +relu, conv3x3 64->64 +relu, maxpool2,
// fc 12544->128 +relu, fc 128->83). bf16 MFMA pipeline, pool-in-register.
//
// ws element(u16) offsets:
//   WB1  @0        : 2048    conv1 W frag [4nt][64lane][8], k==9 slot = bias
//   WB2  @2048     : 36864   conv2 W frag [4nt][18ks][64lane][8], k=(dy*3+dx)*64+ci
//   WFC1 @38912    : 1605632 fc1 W frag [8nt][392ks][64lane][8], k'=(oyp*14+oxp)*64+co
//   WFC2 @1644544  : 12288   fc2 W frag [6nt][4ks][64lane][8] (cls>=83 zeroed)
//   POOL @1656832  : 12845056 pooled acts [1024][12544] bf16 (k'-order)
//   PART @byte 29003776 : f16 fc1 partials [4q][64ig][16img][128fcn] (1MB)
// total 30,052,352 B <= proven ws budget 30,609,408

typedef __attribute__((ext_vector_type(8))) short short8;
typedef __attribute__((ext_vector_type(4))) float f32x4;

#define WB1_E   0u
#define WB2_E   2048u
#define WFC1_E  38912u
#define WFC2_E  1644544u
#define POOL_E  1656832u
#define PART_B  29003776u

__device__ __forceinline__ unsigned short f2bf(float f) {
  unsigned u = __float_as_uint(f);
  u += 0x7fffu + ((u >> 16) & 1u);   // round-to-nearest-even
  return (unsigned short)(u >> 16);
}

// ---------------- prep: repack weights to bf16 frag order ----------------
__global__ __launch_bounds__(256) void prep_kernel(
    const float* __restrict__ w1, const float* __restrict__ c1b,
    const float* __restrict__ w2, const float* __restrict__ wfc1,
    const float* __restrict__ wfc2, unsigned short* __restrict__ ws16)
{
  int i = blockIdx.x * blockDim.x + threadIdx.x;
  if (i < 2048) {
    int j = i & 7, l = (i >> 3) & 63, nt = i >> 9;
    int n = nt * 16 + (l & 15), k = 8 * (l >> 4) + j;
    float v = (k < 9) ? w1[n * 9 + k] : (k == 9 ? c1b[n] : 0.f);
    ws16[WB1_E + i] = f2bf(v);
  } else if (i < 38912) {
    int i2 = i - 2048;
    int j = i2 & 7, l = (i2 >> 3) & 63, rest = i2 >> 9;
    int ks = rest % 18, nt = rest / 18;
    int n = nt * 16 + (l & 15);
    int kk = ks * 32 + 8 * (l >> 4) + j;
    int dydx = kk >> 6, ci = kk & 63;
    ws16[WB2_E + i2] = f2bf(w2[n * 576 + ci * 9 + dydx]);
  } else if (i < 1644544) {
    int i2 = i - 38912;
    int j = i2 & 7, l = (i2 >> 3) & 63, rest = i2 >> 9;
    int ks = rest % 392, nt = rest / 392;
    int fcn = nt * 16 + (l & 15);
    int kp = ks * 32 + 8 * (l >> 4) + j;
    int co = kp & 63, r2 = kp >> 6;
    int oxp = r2 % 14, oyp = r2 / 14;
    ws16[WFC1_E + i2] = f2bf(wfc1[fcn * 12544 + co * 196 + oyp * 14 + oxp]);
  } else if (i < 1656832) {
    int i2 = i - 1644544;
    int j = i2 & 7, l = (i2 >> 3) & 63, rest = i2 >> 9;
    int ks = rest & 3, nt = rest >> 2;
    int cls = nt * 16 + (l & 15);
    int k = ks * 32 + 8 * (l >> 4) + j;
    float v = (cls < 83) ? wfc2[cls * 128 + k] : 0.f;
    ws16[WFC2_E + i2] = f2bf(v);
  }
}

// ---------------- fused conv1+conv2+pool; one (image, row-half) per block ----
// hf=0: out rows 0..15 (4 row-tiles), conv1 rows 0..16
// hf=1: out rows 16..27 (3 row-tiles), conv1 rows 15..27
// LDS: lds1 [18][30][64] bf16 swizzled (69,120 B) + xw 28x28 bf16 (1,568 B)
__global__ __launch_bounds__(512, 4) void conv_kernel(
    const float* __restrict__ x, const float* __restrict__ c2b,
    unsigned short* __restrict__ ws16)
{
  extern __shared__ char smem[];
  unsigned short* xw = (unsigned short*)(smem + 69120);

  const int tid = threadIdx.x;
  const int wave = tid >> 6, lane = tid & 63;
  const int g = lane >> 4, l15 = lane & 15;
  const int bid = blockIdx.x;
  const int n = bid >> 1, hf = bid & 1;
  const int r0 = hf ? 16 : 0;
  const int rlo = hf ? 15 : 0;
  const int M1 = hf ? 364 : 476;   // conv1 positions this half
  const int T1 = hf ? 23 : 30;     // conv1 16-tiles (ceil)
  const int T2 = hf ? 21 : 28;     // conv2 4x4 tiles (exact)

  const short8* wb1 = (const short8*)(ws16 + WB1_E);
  const short8* wb2 = (const short8*)(ws16 + WB2_E);
  unsigned short* poolg = ws16 + POOL_E + (unsigned)n * 12544u;

  short8 z8 = {0, 0, 0, 0, 0, 0, 0, 0};
  short8* l8 = (short8*)smem;
  for (int idx = tid; idx < 4320; idx += 512) l8[idx] = z8;
  {
    const float* xg = x + (n >> 5) * 25088 + (n & 31) * 28;
    for (int i = tid; i < 784; i += 512)
      xw[i] = f2bf(xg[(i / 28) * 896 + (i % 28)]);
  }
  __syncthreads();

  // ---- conv1: weights as A-operand -> thread holds 4 consecutive co -> u32 stores
  {
    short8 b1f[4];
#pragma unroll
    for (int nt = 0; nt < 4; ++nt) b1f[nt] = wb1[nt * 64 + lane];
    for (int mt = wave; mt < T1; mt += 8) {
      int m = mt * 16 + l15;
      bool mval = m < M1;
      int mc = mval ? m : M1 - 1;
      int rr = rlo + mc / 28, ox = mc % 28;
      short8 a;
#pragma unroll
      for (int j = 0; j < 8; ++j) {
        int k = 8 * g + j;
        int dy = (k >= 6) ? 2 : ((k >= 3) ? 1 : 0);
        int dx = k - 3 * dy;
        int iy = rr + dy - 1, ix = ox + dx - 1;
        bool valid = (k < 9) && mval && iy >= 0 && iy < 28 && ix >= 0 && ix < 28;
        int idx = valid ? iy * 28 + ix : 0;
        unsigned short v = xw[idx];
        short r = valid ? (short)v : (short)0;
        a[j] = (k == 9) ? (short)0x3F80 : r;   // bias lane = 1.0
      }
      f32x4 d[4];
#pragma unroll
      for (int nt = 0; nt < 4; ++nt) {
        f32x4 zz = {0.f, 0.f, 0.f, 0.f};
        d[nt] = __builtin_amdgcn_mfma_f32_16x16x32_bf16(b1f[nt], a, zz, 0, 0, 0);
      }
      if (mval) {                       // store col = own l15 -> position m
        int lr = rr - r0 + 1;
        int sp = lr * 30 + ox + 1;
        unsigned base = (unsigned)sp * 128u;
        unsigned swz = ((unsigned)sp & 7u) << 4;
#pragma unroll
        for (int nt = 0; nt < 4; ++nt)
#pragma unroll
          for (int t = 0; t < 2; ++t) {
            int co2 = nt * 16 + 4 * g + 2 * t;
            unsigned pk = (unsigned)f2bf(fmaxf(d[nt][2 * t], 0.f)) |
                          ((unsigned)f2bf(fmaxf(d[nt][2 * t + 1], 0.f)) << 16);
            *(unsigned*)(smem + (base + (((unsigned)(co2 * 2)) ^ swz))) = pk;
          }
      }
    }
  }
  __syncthreads();

  // ---- conv2: M-tile = 4x4 spatial block; thread's 4 acc = one 2x2 pool window
  {
    const int ntp = (wave < 4) ? 0 : 2;
    const int mg = wave & 3;
    float c2bv[2];
#pragma unroll
    for (int tn = 0; tn < 2; ++tn) c2bv[tn] = c2b[(ntp + tn) * 16 + l15];
    const int w4 = l15 >> 2;
    const int oyw = 2 * (w4 >> 1) + ((l15 >> 1) & 1);
    const int oxw = 2 * (w4 & 1) + (l15 & 1);
    int spb[7];
#pragma unroll
    for (int mi = 0; mi < 7; ++mi) {
      int mt = mg + 4 * mi;
      int ryy = (mt * 37) >> 8;          // mt/7 for mt<28
      int rx = mt - 7 * ryy;
      spb[mi] = (4 * ryy + oyw) * 30 + 4 * rx + oxw;
    }
    f32x4 acc[7][2];
#pragma unroll
    for (int mi = 0; mi < 7; ++mi) {
      f32x4 zz = {0.f, 0.f, 0.f, 0.f};
      acc[mi][0] = zz; acc[mi][1] = zz;
    }
#pragma unroll 1
    for (int phase = 0; phase < 6; ++phase) {
      short8 bfr[2][3];
#pragma unroll
      for (int tn = 0; tn < 2; ++tn)
#pragma unroll
        for (int ks = 0; ks < 3; ++ks)
          bfr[tn][ks] = wb2[((ntp + tn) * 18 + phase * 3 + ks) * 64 + lane];
      int dspv[3], cixv[3];
#pragma unroll
      for (int ks = 0; ks < 3; ++ks) {
        int ksg = phase * 3 + ks;
        int dydx = ksg >> 1;
        int dy = (dydx * 11) >> 5;       // dydx/3 for dydx<9
        int dx = dydx - 3 * dy;
        dspv[ks] = dy * 30 + dx;
        cixv[ks] = ((ksg & 1) << 6) + 16 * g;   // = ci0*2
      }
#pragma unroll
      for (int mi = 0; mi < 7; ++mi) {
        int mt = mg + 4 * mi;
        if (mt < T2) {
#pragma unroll
          for (int ks = 0; ks < 3; ++ks) {
            int sp = spb[mi] + dspv[ks];
            unsigned off = (unsigned)sp * 128u +
                           (((unsigned)cixv[ks]) ^ ((((unsigned)sp) & 7u) << 4));
            short8 a = *(const short8*)(smem + off);
            acc[mi][0] = __builtin_amdgcn_mfma_f32_16x16x32_bf16(a, bfr[0][ks], acc[mi][0], 0, 0, 0);
            acc[mi][1] = __builtin_amdgcn_mfma_f32_16x16x32_bf16(a, bfr[1][ks], acc[mi][1], 0, 0, 0);
          }
        }
      }
    }
    // epilogue: bias+relu+2x2 max entirely in-register, direct global store
    const int yb = hf ? 8 : 0;
#pragma unroll
    for (int mi = 0; mi < 7; ++mi) {
      int mt = mg + 4 * mi;
      if (mt < T2) {
        int ryy = (mt * 37) >> 8;
        int rx = mt - 7 * ryy;
        int oyp = yb + 2 * ryy + (g >> 1);
        int oxp = 2 * rx + (g & 1);
#pragma unroll
        for (int tn = 0; tn < 2; ++tn) {
          int co = (ntp + tn) * 16 + l15;
          f32x4 v = acc[mi][tn];
          float p = fmaxf(fmaxf(v[0], v[1]), fmaxf(v[2], v[3]));
          p = fmaxf(p + c2bv[tn], 0.f);
          poolg[(oyp * 14 + oxp) * 64 + co] = f2bf(p);
        }
      }
    }
  }
}

// ---------------- fc1 stage A: 256 blocks = 64 img-groups x 4 K-slices ----
// M=16, N=128 (8 waves x 1 n-tile), K=3136 (98 k-steps), one barrier.
__global__ __launch_bounds__(512) void fc1_kernel(unsigned short* __restrict__ ws16)
{
  extern __shared__ char smem[];
  short8* A8 = (short8*)smem;              // [16 img][393 short8] (stride pad)
  const int tid = threadIdx.x;
  const int wave = tid >> 6, lane = tid & 63;
  const int g = lane >> 4, l15 = lane & 15;
  const int ig = blockIdx.x >> 2, q = blockIdx.x & 3;
  const short8* pool8 = (const short8*)(ws16 + POOL_E);
  const short8* wf1 = (const short8*)(ws16 + WFC1_E);
  {
    int img = tid >> 5, l32 = tid & 31;
    const short8* src = pool8 + (ig * 16 + img) * 1568 + q * 392;
#pragma unroll
    for (int j = 0; j < 13; ++j) {
      int idx = l32 + 32 * j;
      if (idx < 392) A8[img * 393 + idx] = src[idx];
    }
  }
  __syncthreads();
  f32x4 acc = {0.f, 0.f, 0.f, 0.f};
  const short8* wbase = wf1 + (wave * 392 + q * 98) * 64 + lane;
#pragma unroll 2
  for (int ks = 0; ks < 98; ++ks) {
    short8 b = wbase[ks * 64];
    short8 a = A8[l15 * 393 + ks * 4 + g];
    acc = __builtin_amdgcn_mfma_f32_16x16x32_bf16(a, b, acc, 0, 0, 0);
  }
  _Float16* part = (_Float16*)((char*)ws16 + PART_B);
  int base = ((q * 64 + ig) * 16 + 4 * g) * 128 + wave * 16 + l15;
#pragma unroll
  for (int i = 0; i < 4; ++i) part[base + i * 128] = (_Float16)acc[i];
}

// ---------------- fc stage B: sum 4 partials + bias/relu + fc2 ----
__global__ __launch_bounds__(512) void fc2_kernel(
    const float* __restrict__ b1, const float* __restrict__ b2,
    const unsigned short* __restrict__ ws16, float* __restrict__ out)
{
  __shared__ unsigned short h_s[16 * 136];
  const int tid = threadIdx.x;
  const int wave = tid >> 6, lane = tid & 63;
  const int g = lane >> 4, l15 = lane & 15;
  const int ig = blockIdx.x;
  const _Float16* part = (const _Float16*)((const char*)ws16 + PART_B);
#pragma unroll
  for (int t = 0; t < 4; ++t) {
    int u = tid + 512 * t;
    int img = u >> 7, fcn = u & 127;
    float s = 0.f;
#pragma unroll
    for (int q2 = 0; q2 < 4; ++q2)
      s += (float)part[((q2 * 64 + ig) * 16 + img) * 128 + fcn];
    h_s[img * 136 + fcn] = f2bf(fmaxf(s + b1[fcn], 0.f));
  }
  __syncthreads();
  if (wave < 6) {
    const short8* wf2 = (const short8*)(ws16 + WFC2_E);
    const short8* h8 = (const short8*)h_s;
    f32x4 a2 = {0.f, 0.f, 0.f, 0.f};
#pragma unroll
    for (int ks = 0; ks < 4; ++ks) {
      short8 b = wf2[(wave * 4 + ks) * 64 + lane];
      short8 a = h8[l15 * 17 + ks * 4 + g];
      a2 = __builtin_amdgcn_mfma_f32_16x16x32_bf16(a, b, a2, 0, 0, 0);
    }
    int cls = wave * 16 + l15;
    if (cls < 83) {
      float bias2 = b2[cls];
#pragma unroll
      for (int i = 0; i < 4; ++i) {
        int nimg = ig * 16 + 4 * g + i;
        out[((nimg >> 5) * 83 + cls) * 32 + (nimg & 31)] = a2[i] + bias2;
      }
    }
  }
}

extern "C" void kernel_launch(void* const* d_in, const int* in_sizes, int n_in,
                              void* d_out, int out_size, void* d_ws, size_t ws_size,
                              hipStream_t stream)
{
  const float* x    = (const float*)d_in[0];
  const float* w1   = (const float*)d_in[1];
  const float* c1b  = (const float*)d_in[2];
  const float* w2   = (const float*)d_in[3];
  const float* c2b  = (const float*)d_in[4];
  const float* wfc1 = (const float*)d_in[5];
  const float* bfc1 = (const float*)d_in[6];
  const float* wfc2 = (const float*)d_in[7];
  const float* bfc2 = (const float*)d_in[8];
  unsigned short* ws16 = (unsigned short*)d_ws;
  float* out = (float*)d_out;

  prep_kernel<<<6472, 256, 0, stream>>>(w1, c1b, w2, wfc1, wfc2, ws16);
  conv_kernel<<<2048, 512, 70688, stream>>>(x, c2b, ws16);
  fc1_kernel<<<256, 512, 100608, stream>>>(ws16);
  fc2_kernel<<<64, 512, 0, stream>>>(bfc1, bfc2, ws16, out);
}

// Round 3
// 98.226 us; speedup vs baseline: 1.6911x; 1.1217x over previous
//
#include <hip/hip_runtime.h>
#include <hip/hip_bf16.h>

// LineCNNSimple: 1024 x (conv3x3 1->64 +relu, conv3x3 64->64 +relu, maxpool2,
// fc 12544->128 +relu, fc 128->83). bf16 MFMA pipeline, pool-in-register.
// R3: linear 144B-stride LDS (no XOR swizzle -> zero addr VALU per ds_read),
//     divergence-free conv1 A-build from padded 30x30 xw.
//
// ws element(u16) offsets:
//   WB1  @0        : 2048    conv1 W frag [4nt][64lane][8], k==9 slot = bias
//   WB2  @2048     : 36864   conv2 W frag [4nt][18ks][64lane][8], k=(dy*3+dx)*64+ci
//   WFC1 @38912    : 1605632 fc1 W frag [8nt][392ks][64lane][8], k'=(oyp*14+oxp)*64+co
//   WFC2 @1644544  : 12288   fc2 W frag [6nt][4ks][64lane][8] (cls>=83 zeroed)
//   POOL @1656832  : 12845056 pooled acts [1024][12544] bf16 (k'-order)
//   PART @byte 29003776 : f16 fc1 partials [4q][64ig][16img][128fcn] (1MB)

typedef __attribute__((ext_vector_type(8))) short short8;
typedef __attribute__((ext_vector_type(4))) float f32x4;

#define WB1_E   0u
#define WB2_E   2048u
#define WFC1_E  38912u
#define WFC2_E  1644544u
#define POOL_E  1656832u
#define PART_B  29003776u

__device__ __forceinline__ unsigned short f2bf(float f) {
  unsigned u = __float_as_uint(f);
  u += 0x7fffu + ((u >> 16) & 1u);   // round-to-nearest-even
  return (unsigned short)(u >> 16);
}

// ---------------- prep: repack weights to bf16 frag order ----------------
__global__ __launch_bounds__(256) void prep_kernel(
    const float* __restrict__ w1, const float* __restrict__ c1b,
    const float* __restrict__ w2, const float* __restrict__ wfc1,
    const float* __restrict__ wfc2, unsigned short* __restrict__ ws16)
{
  int i = blockIdx.x * blockDim.x + threadIdx.x;
  if (i < 2048) {
    int j = i & 7, l = (i >> 3) & 63, nt = i >> 9;
    int n = nt * 16 + (l & 15), k = 8 * (l >> 4) + j;
    float v = (k < 9) ? w1[n * 9 + k] : (k == 9 ? c1b[n] : 0.f);
    ws16[WB1_E + i] = f2bf(v);
  } else if (i < 38912) {
    int i2 = i - 2048;
    int j = i2 & 7, l = (i2 >> 3) & 63, rest = i2 >> 9;
    int ks = rest % 18, nt = rest / 18;
    int n = nt * 16 + (l & 15);
    int kk = ks * 32 + 8 * (l >> 4) + j;
    int dydx = kk >> 6, ci = kk & 63;
    ws16[WB2_E + i2] = f2bf(w2[n * 576 + ci * 9 + dydx]);
  } else if (i < 1644544) {
    int i2 = i - 38912;
    int j = i2 & 7, l = (i2 >> 3) & 63, rest = i2 >> 9;
    int ks = rest % 392, nt = rest / 392;
    int fcn = nt * 16 + (l & 15);
    int kp = ks * 32 + 8 * (l >> 4) + j;
    int co = kp & 63, r2 = kp >> 6;
    int oxp = r2 % 14, oyp = r2 / 14;
    ws16[WFC1_E + i2] = f2bf(wfc1[fcn * 12544 + co * 196 + oyp * 14 + oxp]);
  } else if (i < 1656832) {
    int i2 = i - 1644544;
    int j = i2 & 7, l = (i2 >> 3) & 63, rest = i2 >> 9;
    int ks = rest & 3, nt = rest >> 2;
    int cls = nt * 16 + (l & 15);
    int k = ks * 32 + 8 * (l >> 4) + j;
    float v = (cls < 83) ? wfc2[cls * 128 + k] : 0.f;
    ws16[WFC2_E + i2] = f2bf(v);
  }
}

// ---------------- fused conv1+conv2+pool; one (image, row-half) per block ----
// lds1: [18 rows][30 cols] cells x 144 B (64 u16 co + 8 u16 pad) = 77,760 B
// xw:   padded 30x30 bf16 input (y,x in [-1,28]) @ 77,760, 1,800 B
__global__ __launch_bounds__(512, 4) void conv_kernel(
    const float* __restrict__ x, const float* __restrict__ c2b,
    unsigned short* __restrict__ ws16)
{
  extern __shared__ char smem[];
  unsigned short* xw = (unsigned short*)(smem + 77760);

  const int tid = threadIdx.x;
  const int wave = tid >> 6, lane = tid & 63;
  const int g = lane >> 4, l15 = lane & 15;
  const int bid = blockIdx.x;
  const int n = bid >> 1, hf = bid & 1;
  const int rlo = hf ? 15 : 0;          // first conv1 output row this half
  const int M1 = hf ? 364 : 476;        // conv1 positions this half
  const int T1 = hf ? 23 : 30;          // conv1 16-tiles (ceil)
  const int T2 = hf ? 21 : 28;          // conv2 4x4 tiles (exact)
  const int lr_off = hf ? -15 : 1;      // store row: lr = rr + lr_off

  const short8* wb1 = (const short8*)(ws16 + WB1_E);
  const short8* wb2 = (const short8*)(ws16 + WB2_E);
  unsigned short* poolg = ws16 + POOL_E + (unsigned)n * 12544u;

  short8 z8 = {0, 0, 0, 0, 0, 0, 0, 0};
  // zero lds1 (incl pads); stage padded window (bounds folded in)
  {
    short8* l8 = (short8*)smem;
    for (int idx = tid; idx < 4860; idx += 512) l8[idx] = z8;
    const float* xg = x + (n >> 5) * 25088 + (n & 31) * 28;
    for (int i = tid; i < 900; i += 512) {
      int yy = (i * 2185) >> 16;        // i/30
      int xx = i - yy * 30;
      int iy = yy - 1, ix = xx - 1;
      bool inb = (iy >= 0) && (iy < 28) && (ix >= 0) && (ix < 28);
      float v = inb ? xg[iy * 896 + ix] : 0.f;
      xw[i] = f2bf(v);
    }
  }
  __syncthreads();

  // ---- conv1: weights as A-operand; A-build with compile-time LDS offsets
  {
    short8 b1f[4];
#pragma unroll
    for (int nt = 0; nt < 4; ++nt) b1f[nt] = wb1[nt * 64 + lane];
    for (int mt = wave; mt < T1; mt += 8) {
      int m = mt * 16 + l15;
      bool mval = m < M1;
      int mc = mval ? m : M1 - 1;
      int yr = (mc * 2341) >> 16;       // mc/28
      int rr = rlo + yr;
      int ox = mc - yr * 28;
      const char* xb = (const char*)xw + (rr * 30 + ox) * 2;
      short8 a = z8;
      if (g == 0) {                     // k = 0..7  (dy*3+dx)
        a[0] = *(const short*)(xb + 0);
        a[1] = *(const short*)(xb + 2);
        a[2] = *(const short*)(xb + 4);
        a[3] = *(const short*)(xb + 60);
        a[4] = *(const short*)(xb + 62);
        a[5] = *(const short*)(xb + 64);
        a[6] = *(const short*)(xb + 120);
        a[7] = *(const short*)(xb + 122);
      } else if (g == 1) {              // k = 8 (dy=2,dx=2), k = 9 bias lane
        a[0] = *(const short*)(xb + 124);
        a[1] = (short)0x3F80;           // 1.0bf16
      }
      f32x4 d[4];
#pragma unroll
      for (int nt = 0; nt < 4; ++nt) {
        f32x4 zz = {0.f, 0.f, 0.f, 0.f};
        d[nt] = __builtin_amdgcn_mfma_f32_16x16x32_bf16(b1f[nt], a, zz, 0, 0, 0);
      }
      if (mval) {                       // D: row=co off 4g+i, col=own l15 -> m
        int spB = ((rr + lr_off) * 30 + ox + 1) * 144;
#pragma unroll
        for (int nt = 0; nt < 4; ++nt)
#pragma unroll
          for (int t = 0; t < 2; ++t) {
            int co2 = nt * 16 + 4 * g + 2 * t;
            unsigned pk = (unsigned)f2bf(fmaxf(d[nt][2 * t], 0.f)) |
                          ((unsigned)f2bf(fmaxf(d[nt][2 * t + 1], 0.f)) << 16);
            *(unsigned*)(smem + (spB + co2 * 2)) = pk;
          }
      }
    }
  }
  __syncthreads();

  // ---- conv2: M-tile = 4x4 spatial block; thread's 4 acc = one 2x2 pool window
  {
    const int ntp = (wave < 4) ? 0 : 2;
    const int mg = wave & 3;
    float c2bv[2];
#pragma unroll
    for (int tn = 0; tn < 2; ++tn) c2bv[tn] = c2b[(ntp + tn) * 16 + l15];
    const int w4 = l15 >> 2;
    const int oyw = 2 * (w4 >> 1) + ((l15 >> 1) & 1);
    const int oxw = 2 * (w4 & 1) + (l15 & 1);
    int baseB[7];                        // per-mi byte base (linear addressing)
#pragma unroll
    for (int mi = 0; mi < 7; ++mi) {
      int mt = mg + 4 * mi;
      int ryy = (mt * 37) >> 8;          // mt/7
      int rx = mt - 7 * ryy;
      baseB[mi] = ((4 * ryy + oyw) * 30 + 4 * rx + oxw) * 144 + 16 * g;
    }
    f32x4 acc[7][2];
#pragma unroll
    for (int mi = 0; mi < 7; ++mi) {
      f32x4 zz = {0.f, 0.f, 0.f, 0.f};
      acc[mi][0] = zz; acc[mi][1] = zz;
    }
#pragma unroll 1
    for (int phase = 0; phase < 6; ++phase) {
      short8 bfr[2][3];
#pragma unroll
      for (int tn = 0; tn < 2; ++tn)
#pragma unroll
        for (int ks = 0; ks < 3; ++ks)
          bfr[tn][ks] = wb2[((ntp + tn) * 18 + phase * 3 + ks) * 64 + lane];
      int dspB[3];                       // wave-uniform (SALU)
#pragma unroll
      for (int ks = 0; ks < 3; ++ks) {
        int ksg = phase * 3 + ks;
        int dydx = ksg >> 1;
        int dy = (dydx * 11) >> 5;       // dydx/3
        int dx = dydx - 3 * dy;
        dspB[ks] = (dy * 30 + dx) * 144 + ((ksg & 1) << 6);
      }
#pragma unroll
      for (int mi = 0; mi < 7; ++mi) {
        int mt = mg + 4 * mi;
        if (mt < T2) {                   // wave-uniform guard
#pragma unroll
          for (int ks = 0; ks < 3; ++ks) {
            short8 a = *(const short8*)(smem + (baseB[mi] + dspB[ks]));
            acc[mi][0] = __builtin_amdgcn_mfma_f32_16x16x32_bf16(a, bfr[0][ks], acc[mi][0], 0, 0, 0);
            acc[mi][1] = __builtin_amdgcn_mfma_f32_16x16x32_bf16(a, bfr[1][ks], acc[mi][1], 0, 0, 0);
          }
        }
      }
    }
    // epilogue: bias+relu+2x2 max entirely in-register, direct global store
    const int yb = hf ? 8 : 0;
#pragma unroll
    for (int mi = 0; mi < 7; ++mi) {
      int mt = mg + 4 * mi;
      if (mt < T2) {
        int ryy = (mt * 37) >> 8;
        int rx = mt - 7 * ryy;
        int oyp = yb + 2 * ryy + (g >> 1);
        int oxp = 2 * rx + (g & 1);
#pragma unroll
        for (int tn = 0; tn < 2; ++tn) {
          int co = (ntp + tn) * 16 + l15;
          f32x4 v = acc[mi][tn];
          float p = fmaxf(fmaxf(v[0], v[1]), fmaxf(v[2], v[3]));
          p = fmaxf(p + c2bv[tn], 0.f);
          poolg[(oyp * 14 + oxp) * 64 + co] = f2bf(p);
        }
      }
    }
  }
}

// ---------------- fc1 stage A: 256 blocks = 64 img-groups x 4 K-slices ----
__global__ __launch_bounds__(512) void fc1_kernel(unsigned short* __restrict__ ws16)
{
  extern __shared__ char smem[];
  short8* A8 = (short8*)smem;              // [16 img][393 short8] (stride pad)
  const int tid = threadIdx.x;
  const int wave = tid >> 6, lane = tid & 63;
  const int g = lane >> 4, l15 = lane & 15;
  const int ig = blockIdx.x >> 2, q = blockIdx.x & 3;
  const short8* pool8 = (const short8*)(ws16 + POOL_E);
  const short8* wf1 = (const short8*)(ws16 + WFC1_E);
  {
    int img = tid >> 5, l32 = tid & 31;
    const short8* src = pool8 + (ig * 16 + img) * 1568 + q * 392;
#pragma unroll
    for (int j = 0; j < 13; ++j) {
      int idx = l32 + 32 * j;
      if (idx < 392) A8[img * 393 + idx] = src[idx];
    }
  }
  __syncthreads();
  f32x4 acc = {0.f, 0.f, 0.f, 0.f};
  const short8* wbase = wf1 + (wave * 392 + q * 98) * 64 + lane;
#pragma unroll 2
  for (int ks = 0; ks < 98; ++ks) {
    short8 b = wbase[ks * 64];
    short8 a = A8[l15 * 393 + ks * 4 + g];
    acc = __builtin_amdgcn_mfma_f32_16x16x32_bf16(a, b, acc, 0, 0, 0);
  }
  _Float16* part = (_Float16*)((char*)ws16 + PART_B);
  int base = ((q * 64 + ig) * 16 + 4 * g) * 128 + wave * 16 + l15;
#pragma unroll
  for (int i = 0; i < 4; ++i) part[base + i * 128] = (_Float16)acc[i];
}

// ---------------- fc stage B: sum 4 partials + bias/relu + fc2 ----
__global__ __launch_bounds__(512) void fc2_kernel(
    const float* __restrict__ b1, const float* __restrict__ b2,
    const unsigned short* __restrict__ ws16, float* __restrict__ out)
{
  __shared__ unsigned short h_s[16 * 136];
  const int tid = threadIdx.x;
  const int wave = tid >> 6, lane = tid & 63;
  const int g = lane >> 4, l15 = lane & 15;
  const int ig = blockIdx.x;
  const _Float16* part = (const _Float16*)((const char*)ws16 + PART_B);
#pragma unroll
  for (int t = 0; t < 4; ++t) {
    int u = tid + 512 * t;
    int img = u >> 7, fcn = u & 127;
    float s = 0.f;
#pragma unroll
    for (int q2 = 0; q2 < 4; ++q2)
      s += (float)part[((q2 * 64 + ig) * 16 + img) * 128 + fcn];
    h_s[img * 136 + fcn] = f2bf(fmaxf(s + b1[fcn], 0.f));
  }
  __syncthreads();
  if (wave < 6) {
    const short8* wf2 = (const short8*)(ws16 + WFC2_E);
    const short8* h8 = (const short8*)h_s;
    f32x4 a2 = {0.f, 0.f, 0.f, 0.f};
#pragma unroll
    for (int ks = 0; ks < 4; ++ks) {
      short8 b = wf2[(wave * 4 + ks) * 64 + lane];
      short8 a = h8[l15 * 17 + ks * 4 + g];
      a2 = __builtin_amdgcn_mfma_f32_16x16x32_bf16(a, b, a2, 0, 0, 0);
    }
    int cls = wave * 16 + l15;
    if (cls < 83) {
      float bias2 = b2[cls];
#pragma unroll
      for (int i = 0; i < 4; ++i) {
        int nimg = ig * 16 + 4 * g + i;
        out[((nimg >> 5) * 83 + cls) * 32 + (nimg & 31)] = a2[i] + bias2;
      }
    }
  }
}

extern "C" void kernel_launch(void* const* d_in, const int* in_sizes, int n_in,
                              void* d_out, int out_size, void* d_ws, size_t ws_size,
                              hipStream_t stream)
{
  const float* x    = (const float*)d_in[0];
  const float* w1   = (const float*)d_in[1];
  const float* c1b  = (const float*)d_in[2];
  const float* w2   = (const float*)d_in[3];
  const float* c2b  = (const float*)d_in[4];
  const float* wfc1 = (const float*)d_in[5];
  const float* bfc1 = (const float*)d_in[6];
  const float* wfc2 = (const float*)d_in[7];
  const float* bfc2 = (const float*)d_in[8];
  unsigned short* ws16 = (unsigned short*)d_ws;
  float* out = (float*)d_out;

  prep_kernel<<<6472, 256, 0, stream>>>(w1, c1b, w2, wfc1, wfc2, ws16);
  conv_kernel<<<2048, 512, 79616, stream>>>(x, c2b, ws16);
  fc1_kernel<<<256, 512, 100608, stream>>>(ws16);
  fc2_kernel<<<64, 512, 0, stream>>>(bfc1, bfc2, ws16, out);
}